// Round 6
// baseline (368.833 us; speedup 1.0000x reference)
//
#include <hip/hip_runtime.h>
#include <hip/hip_bf16.h>

typedef __bf16 bf16;
typedef __bf16 bf16x8 __attribute__((ext_vector_type(8)));
typedef __bf16 bf16x4v __attribute__((ext_vector_type(4)));
typedef float f32x4 __attribute__((ext_vector_type(4)));
typedef float f32x16 __attribute__((ext_vector_type(16)));
typedef float float4v __attribute__((ext_vector_type(4)));
typedef unsigned int uint32x4 __attribute__((ext_vector_type(4)));

#define MFMA16(a, b, c) __builtin_amdgcn_mfma_f32_16x16x32_bf16(a, b, c, 0, 0, 0)
#define MFMA32(a, b, c) __builtin_amdgcn_mfma_f32_32x32x16_bf16(a, b, c, 0, 0, 0)

// q pre-scale: 1/sqrt(64) * log2(e)  (softmax runs in exp2 domain)
#define SCALE_Q 0.1803368801111f

__device__ __forceinline__ void async_load16(const bf16* g, bf16* l) {
    __builtin_amdgcn_global_load_lds(
        (const __attribute__((address_space(1))) void*)g,
        (__attribute__((address_space(3))) void*)l,
        16, 0, 0);
}

__device__ __forceinline__ unsigned int pack2bf(float a, float b) {
    bf16 x = (bf16)a, y = (bf16)b;
    unsigned short ux = __builtin_bit_cast(unsigned short, x);
    unsigned short uy = __builtin_bit_cast(unsigned short, y);
    return (unsigned int)ux | ((unsigned int)uy << 16);
}

// ---------------- cast x (f32 -> bf16), vectorized ----------------
__global__ void k_cast_x(const float* __restrict__ x, bf16* __restrict__ xb, int n4) {
    int i = blockIdx.x * blockDim.x + threadIdx.x;
    if (i < n4) {
        float4v v = ((const float4v*)x)[i];
        bf16x4v o;
        o.x = (bf16)v.x; o.y = (bf16)v.y; o.z = (bf16)v.z; o.w = (bf16)v.w;
        ((bf16x4v*)xb)[i] = o;
    }
}

// ---------------- transpose + cast W (f32 [R][Cc] -> bf16 [Cc][R]) ----------------
__global__ void k_trans_cast(const float* __restrict__ W, bf16* __restrict__ WT, int R, int Cc) {
    __shared__ float tile[32][33];
    int r0 = blockIdx.y * 32, c0 = blockIdx.x * 32;
    int tx = threadIdx.x & 31, ty = threadIdx.x >> 5;
#pragma unroll
    for (int i = 0; i < 32; i += 8)
        tile[ty + i][tx] = W[(size_t)(r0 + ty + i) * Cc + c0 + tx];
    __syncthreads();
#pragma unroll
    for (int i = 0; i < 32; i += 8)
        WT[(size_t)(c0 + ty + i) * R + r0 + tx] = (bf16)tile[tx][ty + i];
}

// ---------------- QKV GEMM with fragment-packed scatter epilogue ----------------
__global__ __launch_bounds__(256, 2) void k_gemm_qkv(
    const bf16* __restrict__ A, const bf16* __restrict__ BT,
    const float* __restrict__ bias,
    bf16* __restrict__ qo, bf16* __restrict__ ko, bf16* __restrict__ vo) {
    __shared__ bf16 As[128 * 32];
    __shared__ bf16 Bs[128 * 32];
    const int K = 1024;
    // XCD-chunked swizzle (bijective: 1536 = 8 * 192): same-XCD blocks share A panels
    int orig = blockIdx.y * 24 + blockIdx.x;
    int wg = (orig & 7) * 192 + (orig >> 3);
    int row0 = (wg / 24) * 128;
    int col0 = (wg % 24) * 128;
    int lane = threadIdx.x & 63, w = threadIdx.x >> 6;
    int wr = w >> 1, wc = w & 1;
    f32x4 acc[4][4] = {};
    const bf16* Ag = A + (size_t)(row0 + (lane >> 2)) * K + (lane & 3) * 8;
    const bf16* Bg = BT + (size_t)(col0 + (lane >> 2)) * K + (lane & 3) * 8;

    for (int k0 = 0; k0 < K; k0 += 32) {
#pragma unroll
        for (int i = 0; i < 2; ++i) {
            async_load16(Ag + (size_t)(i * 64 + w * 16) * K + k0, &As[(i * 64 + w * 16) * 32]);
            async_load16(Bg + (size_t)(i * 64 + w * 16) * K + k0, &Bs[(i * 64 + w * 16) * 32]);
        }
        __syncthreads();
        bf16x8 af[4], bfr[4];
#pragma unroll
        for (int m = 0; m < 4; ++m)
            af[m] = *(const bf16x8*)&As[(wr * 64 + m * 16 + (lane & 15)) * 32 + (lane >> 4) * 8];
#pragma unroll
        for (int n = 0; n < 4; ++n)
            bfr[n] = *(const bf16x8*)&Bs[(wc * 64 + n * 16 + (lane & 15)) * 32 + (lane >> 4) * 8];
#pragma unroll
        for (int m = 0; m < 4; ++m)
#pragma unroll
            for (int n = 0; n < 4; ++n)
                acc[m][n] = MFMA16(af[m], bfr[n], acc[m][n]);
        __syncthreads();
    }

    int trow = row0 + wr * 64 + ((lane >> 4) * 4);
    int tcol = col0 + wc * 64 + (lane & 15);
#pragma unroll
    for (int m = 0; m < 4; ++m)
#pragma unroll
        for (int n = 0; n < 4; ++n) {
            int cg = tcol + n * 16;
            float bi = bias[cg];
#pragma unroll
            for (int j = 0; j < 4; ++j) {
                int rg = trow + m * 16 + j;
                float val = acc[m][n][j] + bi;
                int b = rg >> 11, tt = rg & 2047;
                if (cg < 1024) {
                    int h = cg >> 6, d = cg & 63;
                    size_t base = (size_t)(b * 16 + h) * 131072;
                    size_t idx = base + (size_t)((((tt >> 5) * 4 + (d >> 4)) * 64 + ((d >> 3) & 1) * 32 + (tt & 31)) * 8 + (d & 7));
                    qo[idx] = (bf16)(val * SCALE_Q);
                } else if (cg < 2048) {
                    int c2 = cg - 1024;
                    int h = c2 >> 6, d = c2 & 63;
                    size_t base = (size_t)(b * 16 + h) * 131072;
                    size_t idx = base + (size_t)((((tt >> 5) * 4 + (d >> 4)) * 64 + ((d >> 3) & 1) * 32 + (tt & 31)) * 8 + (d & 7));
                    ko[idx] = (bf16)val;
                } else {
                    int c2 = cg - 2048;
                    int h = c2 >> 6, d = c2 & 63;
                    size_t base = (size_t)(b * 16 + h) * 131072;
                    size_t idx = base + (size_t)(((((tt >> 6) * 4 + ((tt >> 4) & 3)) * 2 + (d >> 5)) * 64 + ((tt >> 3) & 1) * 32 + (d & 31)) * 8 + (tt & 7));
                    vo[idx] = (bf16)val;
                }
            }
        }
}

// ---------------- flash attention (causal), KV-split wave pairs ----------------
// Block = 4 waves = 64 Q-rows: group g = w>>1 owns 32 rows, wave pair (g,half)
// splits KV tiles by parity (ti % 2 == half). Partial (m,l,o) merged via LDS.
// Grid (16,64) paired (bx, 31-bx): 4096 waves -> 4 waves/SIMD.
__global__ __launch_bounds__(256, 4) void k_attn(
    const bf16* __restrict__ qp, const bf16* __restrict__ kp,
    const bf16* __restrict__ vp, bf16* __restrict__ y) {
    __shared__ float Lm[2][64];
    __shared__ float Ll[2][64];
    __shared__ float Lo[2][32 * 64];   // [g][(dt*16+r)*64 + lane]
    int bh = blockIdx.y;
    int b = bh >> 4;
    int lane = threadIdx.x & 63, w = threadIdx.x >> 6;
    int g = w >> 1, half = w & 1;
    int tl = lane & 31, hi = lane >> 5;
    int lane8 = lane * 8;
    const bf16* Qb = qp + (size_t)bh * 131072;
    const bf16* Kb = kp + (size_t)bh * 131072;
    const bf16* Vb = vp + (size_t)bh * 131072;

    for (int qpass = 0; qpass < 2; ++qpass) {
        int qt0 = (qpass ? 31 - (int)blockIdx.x : (int)blockIdx.x) * 64;
        int trow0 = qt0 + g * 32;
        int t_g = trow0 + tl;

        bf16x8 qf[4];
        int qs = (trow0 >> 5) * 4;
#pragma unroll
        for (int kc = 0; kc < 4; ++kc)
            qf[kc] = *(const bf16x8*)&Qb[(qs + kc) * 512 + lane8];

        f32x16 o[2] = {};
        float m = -1e30f, l = 0.f;
        int nt = (trow0 + 95) >> 6;   // tiles covering s <= trow0+31

        bf16x8 kf[8];
        if (half < nt) {
#pragma unroll
            for (int u = 0; u < 8; ++u)
                kf[u] = *(const bf16x8*)&Kb[(half * 8 + u) * 512 + lane8];
        }

        for (int ti = half; ti < nt; ti += 2) {
            int s0 = ti * 64;
            // S^T = K·Q^T
            f32x16 accs[2] = {};
            __builtin_amdgcn_s_setprio(1);
#pragma unroll
            for (int st = 0; st < 2; ++st)
#pragma unroll
                for (int kc = 0; kc < 4; ++kc)
                    accs[st] = MFMA32(kf[st * 4 + kc], qf[kc], accs[st]);
            __builtin_amdgcn_s_setprio(0);

            // prefetch next K tile (stride 2) + this tile's V
            int tin = (ti + 2 < nt) ? ti + 2 : ti;
            bf16x8 kn[8];
#pragma unroll
            for (int u = 0; u < 8; ++u)
                kn[u] = *(const bf16x8*)&Kb[(tin * 8 + u) * 512 + lane8];
            bf16x8 vf[8];
#pragma unroll
            for (int u = 0; u < 8; ++u)
                vf[u] = *(const bf16x8*)&Vb[(ti * 8 + u) * 512 + lane8];

            // causal mask (wave-uniform branch)
            if (s0 + 63 > trow0) {
#pragma unroll
                for (int st = 0; st < 2; ++st)
#pragma unroll
                    for (int r = 0; r < 16; ++r) {
                        int s = s0 + st * 32 + (r & 3) + 8 * (r >> 2) + 4 * hi;
                        if (s > t_g) accs[st][r] = -1e30f;
                    }
            }
            // in-register softmax, exp2 domain; defer-max (skip rescale if max grew < 8)
            float pmax = -1e30f;
#pragma unroll
            for (int st = 0; st < 2; ++st)
#pragma unroll
                for (int r = 0; r < 16; ++r)
                    pmax = fmaxf(pmax, accs[st][r]);
            pmax = fmaxf(pmax, __shfl_xor(pmax, 32));
            if (!__all(pmax <= m + 8.0f)) {
                float mn = fmaxf(m, pmax);
                float corr = __builtin_amdgcn_exp2f(m - mn);
                m = mn;
                l *= corr;
#pragma unroll
                for (int dt = 0; dt < 2; ++dt)
#pragma unroll
                    for (int r = 0; r < 16; ++r)
                        o[dt][r] *= corr;
            }
            float ls = 0.f;
#pragma unroll
            for (int st = 0; st < 2; ++st)
#pragma unroll
                for (int r = 0; r < 16; ++r) {
                    float p = __builtin_amdgcn_exp2f(accs[st][r] - m);
                    accs[st][r] = p;
                    ls += p;
                }
            ls += __shfl_xor(ls, 32);
            l += ls;

            // pack P to bf16 pairs; exchange with pair lane (hi^1). All static idx.
            unsigned int pk[16];
#pragma unroll
            for (int st = 0; st < 2; ++st)
#pragma unroll
                for (int q = 0; q < 8; ++q)
                    pk[st * 8 + q] = pack2bf(accs[st][2 * q], accs[st][2 * q + 1]);
            unsigned int rv[8];
#pragma unroll
            for (int st = 0; st < 2; ++st)
#pragma unroll
                for (int i = 0; i < 4; ++i) {
                    int base = st * 8 + (i < 2 ? i : i + 2);
                    unsigned int send = hi ? pk[base] : pk[base + 2];
                    rv[st * 4 + i] = __shfl_xor(send, 32);
                }
            // PV: O^T = V^T·P^T
            __builtin_amdgcn_s_setprio(1);
#pragma unroll
            for (int c = 0; c < 4; ++c) {
                const int st = c >> 1, c2 = c & 1;
                uint32x4 pw;
                pw.x = hi ? rv[st * 4 + 2 * c2]     : pk[st * 8 + 4 * c2];
                pw.y = hi ? rv[st * 4 + 2 * c2 + 1] : pk[st * 8 + 4 * c2 + 1];
                pw.z = hi ? pk[st * 8 + 4 * c2 + 2] : rv[st * 4 + 2 * c2];
                pw.w = hi ? pk[st * 8 + 4 * c2 + 3] : rv[st * 4 + 2 * c2 + 1];
                bf16x8 pf = __builtin_bit_cast(bf16x8, pw);
#pragma unroll
                for (int dt = 0; dt < 2; ++dt)
                    o[dt] = MFMA32(vf[c * 2 + dt], pf, o[dt]);
            }
            __builtin_amdgcn_s_setprio(0);
#pragma unroll
            for (int u = 0; u < 8; ++u)
                kf[u] = kn[u];
        }

        // merge wave pair (g, 0|1): odd publishes, even combines + writes
        if (half == 1) {
            Lm[g][lane] = m;
            Ll[g][lane] = l;
#pragma unroll
            for (int dt = 0; dt < 2; ++dt)
#pragma unroll
                for (int r = 0; r < 16; ++r)
                    Lo[g][(dt * 16 + r) * 64 + lane] = o[dt][r];
        }
        __syncthreads();
        if (half == 0) {
            float m1 = Lm[g][lane], l1 = Ll[g][lane];
            float mn = fmaxf(m, m1);
            float c0 = __builtin_amdgcn_exp2f(m - mn);
            float c1 = __builtin_amdgcn_exp2f(m1 - mn);
            float inv = 1.0f / (l * c0 + l1 * c1);
            int hcol = (bh & 15) * 64;
            bf16* yr = y + (size_t)(b * 2048 + t_g) * 1024 + hcol;
#pragma unroll
            for (int dt = 0; dt < 2; ++dt)
#pragma unroll
                for (int rq = 0; rq < 4; ++rq) {
                    bf16x4v ov;
#pragma unroll
                    for (int ri = 0; ri < 4; ++ri) {
                        int r = rq * 4 + ri;
                        float vv = o[dt][r] * c0 + Lo[g][(dt * 16 + r) * 64 + lane] * c1;
                        ov[ri] = (bf16)(vv * inv);
                    }
                    *(bf16x4v*)&yr[dt * 32 + rq * 8 + hi * 4] = ov;
                }
        }
        __syncthreads();   // protect LDS reuse across passes
    }
}

// ---------------- proj GEMM: y[8192x1024] x Wp[1024x1024] + bias -> f32 out ----------------
__global__ __launch_bounds__(256, 2) void k_gemm_proj(
    const bf16* __restrict__ A, const bf16* __restrict__ BT,
    const float* __restrict__ bias, float* __restrict__ out) {
    __shared__ bf16 As[128 * 32];
    __shared__ bf16 Bs[128 * 32];
    const int K = 1024;
    // XCD-chunked swizzle (bijective: 512 = 8 * 64)
    int orig = blockIdx.y * 8 + blockIdx.x;
    int wg = (orig & 7) * 64 + (orig >> 3);
    int row0 = (wg >> 3) * 128;
    int col0 = (wg & 7) * 128;
    int lane = threadIdx.x & 63, w = threadIdx.x >> 6;
    int wr = w >> 1, wc = w & 1;
    f32x4 acc[4][4] = {};
    const bf16* Ag = A + (size_t)(row0 + (lane >> 2)) * K + (lane & 3) * 8;
    const bf16* Bg = BT + (size_t)(col0 + (lane >> 2)) * K + (lane & 3) * 8;

    for (int k0 = 0; k0 < K; k0 += 32) {
#pragma unroll
        for (int i = 0; i < 2; ++i) {
            async_load16(Ag + (size_t)(i * 64 + w * 16) * K + k0, &As[(i * 64 + w * 16) * 32]);
            async_load16(Bg + (size_t)(i * 64 + w * 16) * K + k0, &Bs[(i * 64 + w * 16) * 32]);
        }
        __syncthreads();
        bf16x8 af[4], bfr[4];
#pragma unroll
        for (int m = 0; m < 4; ++m)
            af[m] = *(const bf16x8*)&As[(wr * 64 + m * 16 + (lane & 15)) * 32 + (lane >> 4) * 8];
#pragma unroll
        for (int n = 0; n < 4; ++n)
            bfr[n] = *(const bf16x8*)&Bs[(wc * 64 + n * 16 + (lane & 15)) * 32 + (lane >> 4) * 8];
#pragma unroll
        for (int m = 0; m < 4; ++m)
#pragma unroll
            for (int n = 0; n < 4; ++n)
                acc[m][n] = MFMA16(af[m], bfr[n], acc[m][n]);
        __syncthreads();
    }

    int trow = row0 + wr * 64 + ((lane >> 4) * 4);
    int tcol = col0 + wc * 64 + (lane & 15);
#pragma unroll
    for (int m = 0; m < 4; ++m)
#pragma unroll
        for (int n = 0; n < 4; ++n) {
            int cg = tcol + n * 16;
            float bi = bias[cg];
#pragma unroll
            for (int j = 0; j < 4; ++j) {
                int rg = trow + m * 16 + j;
                out[(size_t)rg * 1024 + cg] = acc[m][n][j] + bi;
            }
        }
}

// ---------------- new_memory = x[:, 1536:, :] (f32 copy) ----------------
__global__ void k_copy_mem(const float* __restrict__ x, float* __restrict__ out2) {
    int o4 = blockIdx.x * blockDim.x + threadIdx.x;
    if (o4 < 524288) {
        int b = o4 >> 17;
        int rem = o4 & 131071;
        ((float4v*)out2)[o4] = ((const float4v*)x)[(size_t)b * 524288 + 393216 + rem];
    }
}

extern "C" void kernel_launch(void* const* d_in, const int* in_sizes, int n_in,
                              void* d_out, int out_size, void* d_ws, size_t ws_size,
                              hipStream_t stream) {
    const float* x = (const float*)d_in[0];
    const float* W_attn = (const float*)d_in[1];
    const float* b_attn = (const float*)d_in[2];
    const float* W_proj = (const float*)d_in[3];
    const float* b_proj = (const float*)d_in[4];
    float* out = (float*)d_out;
    float* out_mem = out + (size_t)8388608;

    char* ws = (char*)d_ws;
    bf16* xb  = (bf16*)(ws);                         // 16MB  [8192][1024]
    bf16* WaT = (bf16*)(ws + ((size_t)16 << 20));    // 6MB   [3072][1024]
    bf16* WpT = (bf16*)(ws + ((size_t)22 << 20));    // 2MB   [1024][1024]
    bf16* q   = (bf16*)(ws + ((size_t)24 << 20));    // 16MB  packed frags
    bf16* k   = (bf16*)(ws + ((size_t)40 << 20));    // 16MB  packed frags
    bf16* vT  = (bf16*)(ws + ((size_t)56 << 20));    // 16MB  packed frags
    bf16* y   = (bf16*)(ws + ((size_t)72 << 20));    // 16MB  [8192][1024]

    k_cast_x<<<8192, 256, 0, stream>>>(x, xb, 2097152);
    k_trans_cast<<<dim3(96, 32), 256, 0, stream>>>(W_attn, WaT, 1024, 3072);
    k_trans_cast<<<dim3(32, 32), 256, 0, stream>>>(W_proj, WpT, 1024, 1024);
    k_gemm_qkv<<<dim3(24, 64), 256, 0, stream>>>(xb, WaT, b_attn, q, k, vT);
    k_attn<<<dim3(16, 64), 256, 0, stream>>>(q, k, vT, y);
    k_gemm_proj<<<dim3(8, 64), 256, 0, stream>>>(y, WpT, b_proj, out);
    k_copy_mem<<<2048, 256, 0, stream>>>(x, out_mem);
}

// Round 7
// 195.778 us; speedup vs baseline: 1.8839x; 1.8839x over previous
//
#include <hip/hip_runtime.h>
#include <hip/hip_bf16.h>

typedef __bf16 bf16;
typedef __bf16 bf16x8 __attribute__((ext_vector_type(8)));
typedef __bf16 bf16x4v __attribute__((ext_vector_type(4)));
typedef float f32x4 __attribute__((ext_vector_type(4)));
typedef float f32x16 __attribute__((ext_vector_type(16)));
typedef float float4v __attribute__((ext_vector_type(4)));
typedef unsigned int uint32x4 __attribute__((ext_vector_type(4)));

#define MFMA16(a, b, c) __builtin_amdgcn_mfma_f32_16x16x32_bf16(a, b, c, 0, 0, 0)
#define MFMA32(a, b, c) __builtin_amdgcn_mfma_f32_32x32x16_bf16(a, b, c, 0, 0, 0)

// q pre-scale: 1/sqrt(64) * log2(e)  (softmax runs in exp2 domain)
#define SCALE_Q 0.1803368801111f

__device__ __forceinline__ void async_load16(const bf16* g, bf16* l) {
    __builtin_amdgcn_global_load_lds(
        (const __attribute__((address_space(1))) void*)g,
        (__attribute__((address_space(3))) void*)l,
        16, 0, 0);
}

__device__ __forceinline__ unsigned int pack2bf(float a, float b) {
    bf16 x = (bf16)a, y = (bf16)b;
    unsigned short ux = __builtin_bit_cast(unsigned short, x);
    unsigned short uy = __builtin_bit_cast(unsigned short, y);
    return (unsigned int)ux | ((unsigned int)uy << 16);
}

// ---------------- cast x (f32 -> bf16), vectorized ----------------
__global__ void k_cast_x(const float* __restrict__ x, bf16* __restrict__ xb, int n4) {
    int i = blockIdx.x * blockDim.x + threadIdx.x;
    if (i < n4) {
        float4v v = ((const float4v*)x)[i];
        bf16x4v o;
        o.x = (bf16)v.x; o.y = (bf16)v.y; o.z = (bf16)v.z; o.w = (bf16)v.w;
        ((bf16x4v*)xb)[i] = o;
    }
}

// ---------------- transpose + cast W (f32 [R][Cc] -> bf16 [Cc][R]) ----------------
__global__ void k_trans_cast(const float* __restrict__ W, bf16* __restrict__ WT, int R, int Cc) {
    __shared__ float tile[32][33];
    int r0 = blockIdx.y * 32, c0 = blockIdx.x * 32;
    int tx = threadIdx.x & 31, ty = threadIdx.x >> 5;
#pragma unroll
    for (int i = 0; i < 32; i += 8)
        tile[ty + i][tx] = W[(size_t)(r0 + ty + i) * Cc + c0 + tx];
    __syncthreads();
#pragma unroll
    for (int i = 0; i < 32; i += 8)
        WT[(size_t)(c0 + ty + i) * R + r0 + tx] = (bf16)tile[tx][ty + i];
}

// ---------------- QKV GEMM with fragment-packed scatter epilogue ----------------
__global__ __launch_bounds__(256, 2) void k_gemm_qkv(
    const bf16* __restrict__ A, const bf16* __restrict__ BT,
    const float* __restrict__ bias,
    bf16* __restrict__ qo, bf16* __restrict__ ko, bf16* __restrict__ vo) {
    __shared__ bf16 As[128 * 32];
    __shared__ bf16 Bs[128 * 32];
    const int K = 1024;
    // XCD-chunked swizzle (bijective: 1536 = 8 * 192)
    int orig = blockIdx.y * 24 + blockIdx.x;
    int wg = (orig & 7) * 192 + (orig >> 3);
    int row0 = (wg / 24) * 128;
    int col0 = (wg % 24) * 128;
    int lane = threadIdx.x & 63, w = threadIdx.x >> 6;
    int wr = w >> 1, wc = w & 1;
    f32x4 acc[4][4] = {};
    const bf16* Ag = A + (size_t)(row0 + (lane >> 2)) * K + (lane & 3) * 8;
    const bf16* Bg = BT + (size_t)(col0 + (lane >> 2)) * K + (lane & 3) * 8;

    for (int k0 = 0; k0 < K; k0 += 32) {
#pragma unroll
        for (int i = 0; i < 2; ++i) {
            async_load16(Ag + (size_t)(i * 64 + w * 16) * K + k0, &As[(i * 64 + w * 16) * 32]);
            async_load16(Bg + (size_t)(i * 64 + w * 16) * K + k0, &Bs[(i * 64 + w * 16) * 32]);
        }
        __syncthreads();
        bf16x8 af[4], bfr[4];
#pragma unroll
        for (int m = 0; m < 4; ++m)
            af[m] = *(const bf16x8*)&As[(wr * 64 + m * 16 + (lane & 15)) * 32 + (lane >> 4) * 8];
#pragma unroll
        for (int n = 0; n < 4; ++n)
            bfr[n] = *(const bf16x8*)&Bs[(wc * 64 + n * 16 + (lane & 15)) * 32 + (lane >> 4) * 8];
#pragma unroll
        for (int m = 0; m < 4; ++m)
#pragma unroll
            for (int n = 0; n < 4; ++n)
                acc[m][n] = MFMA16(af[m], bfr[n], acc[m][n]);
        __syncthreads();
    }

    int trow = row0 + wr * 64 + ((lane >> 4) * 4);
    int tcol = col0 + wc * 64 + (lane & 15);
#pragma unroll
    for (int m = 0; m < 4; ++m)
#pragma unroll
        for (int n = 0; n < 4; ++n) {
            int cg = tcol + n * 16;
            float bi = bias[cg];
#pragma unroll
            for (int j = 0; j < 4; ++j) {
                int rg = trow + m * 16 + j;
                float val = acc[m][n][j] + bi;
                int b = rg >> 11, tt = rg & 2047;
                if (cg < 1024) {
                    int h = cg >> 6, d = cg & 63;
                    size_t base = (size_t)(b * 16 + h) * 131072;
                    size_t idx = base + (size_t)((((tt >> 5) * 4 + (d >> 4)) * 64 + ((d >> 3) & 1) * 32 + (tt & 31)) * 8 + (d & 7));
                    qo[idx] = (bf16)(val * SCALE_Q);
                } else if (cg < 2048) {
                    int c2 = cg - 1024;
                    int h = c2 >> 6, d = c2 & 63;
                    size_t base = (size_t)(b * 16 + h) * 131072;
                    size_t idx = base + (size_t)((((tt >> 5) * 4 + (d >> 4)) * 64 + ((d >> 3) & 1) * 32 + (tt & 31)) * 8 + (d & 7));
                    ko[idx] = (bf16)val;
                } else {
                    int c2 = cg - 2048;
                    int h = c2 >> 6, d = c2 & 63;
                    size_t base = (size_t)(b * 16 + h) * 131072;
                    size_t idx = base + (size_t)(((((tt >> 6) * 4 + ((tt >> 4) & 3)) * 2 + (d >> 5)) * 64 + ((tt >> 3) & 1) * 32 + (d & 31)) * 8 + (tt & 7));
                    vo[idx] = (bf16)val;
                }
            }
        }
}

// ---------------- flash attention (causal), LDS-shared K/V tiles ----------------
// 4 waves x 32 Q-rows = 128-row Q-tile per pass; 2 passes (bx, 15-bx): 34
// tile-units/block uniform. K/V tiles (16KB) double-buffered in LDS, shared by
// all 4 waves (cuts L2 request traffic 4x). Packed layout => staging is the
// native global_load_lds pattern (uniform base + lane*16B), LDS reads are
// linear ds_read_b128: NO swizzle anywhere. r2-proven sync skeleton.
__global__ __launch_bounds__(256, 2) void k_attn(
    const bf16* __restrict__ qp, const bf16* __restrict__ kp,
    const bf16* __restrict__ vp, bf16* __restrict__ y) {
    __shared__ __align__(16) bf16 Ks[2][4096];
    __shared__ __align__(16) bf16 Vs[2][4096];
    int bh = blockIdx.y;
    int b = bh >> 4;
    int lane = threadIdx.x & 63, w = threadIdx.x >> 6;
    int tl = lane & 31, hi = lane >> 5;
    int lane8 = lane * 8;
    const bf16* Qb = qp + (size_t)bh * 131072;
    const bf16* Kb = kp + (size_t)bh * 131072;
    const bf16* Vb = vp + (size_t)bh * 131072;

    for (int qpass = 0; qpass < 2; ++qpass) {
        int qt0 = (qpass ? 15 - (int)blockIdx.x : (int)blockIdx.x) * 128;
        int trow0 = qt0 + w * 32;
        int t_g = trow0 + tl;

        bf16x8 qf[4];
        int qs = (trow0 >> 5) * 4;
#pragma unroll
        for (int kc = 0; kc < 4; ++kc)
            qf[kc] = *(const bf16x8*)&Qb[(qs + kc) * 512 + lane8];

        f32x16 o[2] = {};
        float m = -1e30f, l = 0.f;
        int ntb = (qt0 >> 6) + 2;   // block-uniform tile count
        int cur = 0;

        // prologue: stage tile 0 into buf 0 (wave w stages chunks 2w, 2w+1)
#pragma unroll
        for (int i = 0; i < 2; ++i) {
            int u = 2 * w + i;
            async_load16(Kb + (size_t)u * 512 + lane8, &Ks[0][u * 512]);
            async_load16(Vb + (size_t)u * 512 + lane8, &Vs[0][u * 512]);
        }
        __syncthreads();

        for (int ti = 0; ti < ntb; ++ti) {
            int s0 = ti * 64;
            if (ti + 1 < ntb) {
#pragma unroll
                for (int i = 0; i < 2; ++i) {
                    int u = 2 * w + i;
                    async_load16(Kb + (size_t)((ti + 1) * 8 + u) * 512 + lane8, &Ks[cur ^ 1][u * 512]);
                    async_load16(Vb + (size_t)((ti + 1) * 8 + u) * 512 + lane8, &Vs[cur ^ 1][u * 512]);
                }
            }
            if (s0 < trow0 + 32) {
                // S^T = K·Q^T  (K fragments from shared LDS, linear b128 reads)
                f32x16 accs[2] = {};
                __builtin_amdgcn_s_setprio(1);
#pragma unroll
                for (int st = 0; st < 2; ++st)
#pragma unroll
                    for (int kc = 0; kc < 4; ++kc) {
                        bf16x8 kf = *(const bf16x8*)&Ks[cur][(st * 4 + kc) * 512 + lane8];
                        accs[st] = MFMA32(kf, qf[kc], accs[st]);
                    }
                __builtin_amdgcn_s_setprio(0);

                // causal mask (wave-uniform branch)
                if (s0 + 63 > trow0) {
#pragma unroll
                    for (int st = 0; st < 2; ++st)
#pragma unroll
                        for (int r = 0; r < 16; ++r) {
                            int s = s0 + st * 32 + (r & 3) + 8 * (r >> 2) + 4 * hi;
                            if (s > t_g) accs[st][r] = -1e30f;
                        }
                }
                // in-register softmax, exp2 domain; defer-max rescale
                float pmax = -1e30f;
#pragma unroll
                for (int st = 0; st < 2; ++st)
#pragma unroll
                    for (int r = 0; r < 16; ++r)
                        pmax = fmaxf(pmax, accs[st][r]);
                pmax = fmaxf(pmax, __shfl_xor(pmax, 32));
                if (!__all(pmax <= m + 8.0f)) {
                    float mn = fmaxf(m, pmax);
                    float corr = __builtin_amdgcn_exp2f(m - mn);
                    m = mn;
                    l *= corr;
#pragma unroll
                    for (int dt = 0; dt < 2; ++dt)
#pragma unroll
                        for (int r = 0; r < 16; ++r)
                            o[dt][r] *= corr;
                }
                float ls = 0.f;
#pragma unroll
                for (int st = 0; st < 2; ++st)
#pragma unroll
                    for (int r = 0; r < 16; ++r) {
                        float p = __builtin_amdgcn_exp2f(accs[st][r] - m);
                        accs[st][r] = p;
                        ls += p;
                    }
                ls += __shfl_xor(ls, 32);
                l += ls;

                // pack P to bf16 pairs; exchange with pair lane (hi^1). Static idx.
                unsigned int pk[16];
#pragma unroll
                for (int st = 0; st < 2; ++st)
#pragma unroll
                    for (int q = 0; q < 8; ++q)
                        pk[st * 8 + q] = pack2bf(accs[st][2 * q], accs[st][2 * q + 1]);
                unsigned int rv[8];
#pragma unroll
                for (int st = 0; st < 2; ++st)
#pragma unroll
                    for (int i = 0; i < 4; ++i) {
                        int base = st * 8 + (i < 2 ? i : i + 2);
                        unsigned int send = hi ? pk[base] : pk[base + 2];
                        rv[st * 4 + i] = __shfl_xor(send, 32);
                    }
                // PV: O^T = V^T·P^T (V fragments JIT from shared LDS)
                __builtin_amdgcn_s_setprio(1);
#pragma unroll
                for (int c = 0; c < 4; ++c) {
                    const int st = c >> 1, c2 = c & 1;
                    uint32x4 pw;
                    pw.x = hi ? rv[st * 4 + 2 * c2]     : pk[st * 8 + 4 * c2];
                    pw.y = hi ? rv[st * 4 + 2 * c2 + 1] : pk[st * 8 + 4 * c2 + 1];
                    pw.z = hi ? pk[st * 8 + 4 * c2 + 2] : rv[st * 4 + 2 * c2];
                    pw.w = hi ? pk[st * 8 + 4 * c2 + 3] : rv[st * 4 + 2 * c2 + 1];
                    bf16x8 pf = __builtin_bit_cast(bf16x8, pw);
#pragma unroll
                    for (int dt = 0; dt < 2; ++dt) {
                        bf16x8 vf = *(const bf16x8*)&Vs[cur][(c * 2 + dt) * 512 + lane8];
                        o[dt] = MFMA32(vf, pf, o[dt]);
                    }
                }
                __builtin_amdgcn_s_setprio(0);
            }
            __syncthreads();   // drains stage vmcnt + orders buffer reuse
            cur ^= 1;
        }

        int hcol = (bh & 15) * 64;
        float inv = 1.0f / l;
        bf16* yr = y + (size_t)(b * 2048 + t_g) * 1024 + hcol;
#pragma unroll
        for (int dt = 0; dt < 2; ++dt)
#pragma unroll
            for (int rq = 0; rq < 4; ++rq) {
                bf16x4v ov;
#pragma unroll
                for (int ri = 0; ri < 4; ++ri)
                    ov[ri] = (bf16)(o[dt][rq * 4 + ri] * inv);
                *(bf16x4v*)&yr[dt * 32 + rq * 8 + hi * 4] = ov;
            }
    }
}

// ---------------- proj GEMM: y[8192x1024] x Wp[1024x1024] + bias -> f32 out ----------------
__global__ __launch_bounds__(256, 2) void k_gemm_proj(
    const bf16* __restrict__ A, const bf16* __restrict__ BT,
    const float* __restrict__ bias, float* __restrict__ out) {
    __shared__ bf16 As[128 * 32];
    __shared__ bf16 Bs[128 * 32];
    const int K = 1024;
    // XCD-chunked swizzle (bijective: 512 = 8 * 64)
    int orig = blockIdx.y * 8 + blockIdx.x;
    int wg = (orig & 7) * 64 + (orig >> 3);
    int row0 = (wg >> 3) * 128;
    int col0 = (wg & 7) * 128;
    int lane = threadIdx.x & 63, w = threadIdx.x >> 6;
    int wr = w >> 1, wc = w & 1;
    f32x4 acc[4][4] = {};
    const bf16* Ag = A + (size_t)(row0 + (lane >> 2)) * K + (lane & 3) * 8;
    const bf16* Bg = BT + (size_t)(col0 + (lane >> 2)) * K + (lane & 3) * 8;

    for (int k0 = 0; k0 < K; k0 += 32) {
#pragma unroll
        for (int i = 0; i < 2; ++i) {
            async_load16(Ag + (size_t)(i * 64 + w * 16) * K + k0, &As[(i * 64 + w * 16) * 32]);
            async_load16(Bg + (size_t)(i * 64 + w * 16) * K + k0, &Bs[(i * 64 + w * 16) * 32]);
        }
        __syncthreads();
        bf16x8 af[4], bfr[4];
#pragma unroll
        for (int m = 0; m < 4; ++m)
            af[m] = *(const bf16x8*)&As[(wr * 64 + m * 16 + (lane & 15)) * 32 + (lane >> 4) * 8];
#pragma unroll
        for (int n = 0; n < 4; ++n)
            bfr[n] = *(const bf16x8*)&Bs[(wc * 64 + n * 16 + (lane & 15)) * 32 + (lane >> 4) * 8];
#pragma unroll
        for (int m = 0; m < 4; ++m)
#pragma unroll
            for (int n = 0; n < 4; ++n)
                acc[m][n] = MFMA16(af[m], bfr[n], acc[m][n]);
        __syncthreads();
    }

    int trow = row0 + wr * 64 + ((lane >> 4) * 4);
    int tcol = col0 + wc * 64 + (lane & 15);
#pragma unroll
    for (int m = 0; m < 4; ++m)
#pragma unroll
        for (int n = 0; n < 4; ++n) {
            int cg = tcol + n * 16;
            float bi = bias[cg];
#pragma unroll
            for (int j = 0; j < 4; ++j) {
                int rg = trow + m * 16 + j;
                out[(size_t)rg * 1024 + cg] = acc[m][n][j] + bi;
            }
        }
}

// ---------------- new_memory = x[:, 1536:, :] (f32 copy) ----------------
__global__ void k_copy_mem(const float* __restrict__ x, float* __restrict__ out2) {
    int o4 = blockIdx.x * blockDim.x + threadIdx.x;
    if (o4 < 524288) {
        int b = o4 >> 17;
        int rem = o4 & 131071;
        ((float4v*)out2)[o4] = ((const float4v*)x)[(size_t)b * 524288 + 393216 + rem];
    }
}

extern "C" void kernel_launch(void* const* d_in, const int* in_sizes, int n_in,
                              void* d_out, int out_size, void* d_ws, size_t ws_size,
                              hipStream_t stream) {
    const float* x = (const float*)d_in[0];
    const float* W_attn = (const float*)d_in[1];
    const float* b_attn = (const float*)d_in[2];
    const float* W_proj = (const float*)d_in[3];
    const float* b_proj = (const float*)d_in[4];
    float* out = (float*)d_out;
    float* out_mem = out + (size_t)8388608;

    char* ws = (char*)d_ws;
    bf16* xb  = (bf16*)(ws);                         // 16MB  [8192][1024]
    bf16* WaT = (bf16*)(ws + ((size_t)16 << 20));    // 6MB   [3072][1024]
    bf16* WpT = (bf16*)(ws + ((size_t)22 << 20));    // 2MB   [1024][1024]
    bf16* q   = (bf16*)(ws + ((size_t)24 << 20));    // 16MB  packed frags
    bf16* k   = (bf16*)(ws + ((size_t)40 << 20));    // 16MB  packed frags
    bf16* vT  = (bf16*)(ws + ((size_t)56 << 20));    // 16MB  packed frags
    bf16* y   = (bf16*)(ws + ((size_t)72 << 20));    // 16MB  [8192][1024]

    k_cast_x<<<8192, 256, 0, stream>>>(x, xb, 2097152);
    k_trans_cast<<<dim3(96, 32), 256, 0, stream>>>(W_attn, WaT, 1024, 3072);
    k_trans_cast<<<dim3(32, 32), 256, 0, stream>>>(W_proj, WpT, 1024, 1024);
    k_gemm_qkv<<<dim3(24, 64), 256, 0, stream>>>(xb, WaT, b_attn, q, k, vT);
    k_attn<<<dim3(8, 64), 256, 0, stream>>>(q, k, vT, y);
    k_gemm_proj<<<dim3(8, 64), 256, 0, stream>>>(y, WpT, b_proj, out);
    k_copy_mem<<<2048, 256, 0, stream>>>(x, out_mem);
}

// Round 8
// 195.063 us; speedup vs baseline: 1.8908x; 1.0037x over previous
//
#include <hip/hip_runtime.h>
#include <hip/hip_bf16.h>

typedef __bf16 bf16;
typedef __bf16 bf16x8 __attribute__((ext_vector_type(8)));
typedef __bf16 bf16x4v __attribute__((ext_vector_type(4)));
typedef float f32x4 __attribute__((ext_vector_type(4)));
typedef float f32x16 __attribute__((ext_vector_type(16)));
typedef float float4v __attribute__((ext_vector_type(4)));
typedef unsigned int uint32x4 __attribute__((ext_vector_type(4)));

#define MFMA16(a, b, c) __builtin_amdgcn_mfma_f32_16x16x32_bf16(a, b, c, 0, 0, 0)
#define MFMA32(a, b, c) __builtin_amdgcn_mfma_f32_32x32x16_bf16(a, b, c, 0, 0, 0)

// q pre-scale: 1/sqrt(64) * log2(e)  (softmax runs in exp2 domain)
#define SCALE_Q 0.1803368801111f

__device__ __forceinline__ void async_load16(const bf16* g, bf16* l) {
    __builtin_amdgcn_global_load_lds(
        (const __attribute__((address_space(1))) void*)g,
        (__attribute__((address_space(3))) void*)l,
        16, 0, 0);
}

__device__ __forceinline__ unsigned int pack2bf(float a, float b) {
    bf16 x = (bf16)a, y = (bf16)b;
    unsigned short ux = __builtin_bit_cast(unsigned short, x);
    unsigned short uy = __builtin_bit_cast(unsigned short, y);
    return (unsigned int)ux | ((unsigned int)uy << 16);
}

// ---------------- cast x (f32 -> bf16) + fused new_memory copy ----------------
__global__ void k_cast_x(const float* __restrict__ x, bf16* __restrict__ xb,
                         float* __restrict__ out_mem) {
    int i = blockIdx.x * blockDim.x + threadIdx.x;   // float4 index, 2097152 total
    if (i < 2097152) {
        float4v v = ((const float4v*)x)[i];
        bf16x4v o;
        o.x = (bf16)v.x; o.y = (bf16)v.y; o.z = (bf16)v.z; o.w = (bf16)v.w;
        ((bf16x4v*)xb)[i] = o;
        int rem = i & 524287;                        // within-batch float4 idx
        if (rem >= 393216) {                         // t >= 1536
            int b = i >> 19;
            ((float4v*)out_mem)[(size_t)b * 131072 + (rem - 393216)] = v;
        }
    }
}

// ---------------- transpose + cast W (f32 [R][Cc] -> bf16 [Cc][R]) ----------------
__global__ void k_trans_cast(const float* __restrict__ W, bf16* __restrict__ WT, int R, int Cc) {
    __shared__ float tile[32][33];
    int r0 = blockIdx.y * 32, c0 = blockIdx.x * 32;
    int tx = threadIdx.x & 31, ty = threadIdx.x >> 5;
#pragma unroll
    for (int i = 0; i < 32; i += 8)
        tile[ty + i][tx] = W[(size_t)(r0 + ty + i) * Cc + c0 + tx];
    __syncthreads();
#pragma unroll
    for (int i = 0; i < 32; i += 8)
        WT[(size_t)(c0 + ty + i) * R + r0 + tx] = (bf16)tile[tx][ty + i];
}

// ---------------- QKV GEMM: prefetch-pipelined 2-phase, packed scatter epilogue ----------------
__global__ __launch_bounds__(256, 4) void k_gemm_qkv(
    const bf16* __restrict__ A, const bf16* __restrict__ BT,
    const float* __restrict__ bias,
    bf16* __restrict__ qo, bf16* __restrict__ ko, bf16* __restrict__ vo) {
    __shared__ bf16 As[2][128 * 32];
    __shared__ bf16 Bs[2][128 * 32];
    const int K = 1024;
    // XCD-chunked swizzle (bijective: 1536 = 8 * 192)
    int orig = blockIdx.y * 24 + blockIdx.x;
    int wg = (orig & 7) * 192 + (orig >> 3);
    int row0 = (wg / 24) * 128;
    int col0 = (wg % 24) * 128;
    int lane = threadIdx.x & 63, w = threadIdx.x >> 6;
    int wr = w >> 1, wc = w & 1;
    f32x4 acc[4][4] = {};
    const bf16* Ag = A + (size_t)(row0 + (lane >> 2)) * K + (lane & 3) * 8;
    const bf16* Bg = BT + (size_t)(col0 + (lane >> 2)) * K + (lane & 3) * 8;

    // prologue: stage k0=0 into buf 0
#pragma unroll
    for (int i = 0; i < 2; ++i) {
        async_load16(Ag + (size_t)(i * 64 + w * 16) * K, &As[0][(i * 64 + w * 16) * 32]);
        async_load16(Bg + (size_t)(i * 64 + w * 16) * K, &Bs[0][(i * 64 + w * 16) * 32]);
    }
    __syncthreads();
    int cur = 0;

    for (int k0 = 0; k0 < K; k0 += 32) {
        if (k0 + 32 < K) {
#pragma unroll
            for (int i = 0; i < 2; ++i) {
                async_load16(Ag + (size_t)(i * 64 + w * 16) * K + (k0 + 32), &As[cur ^ 1][(i * 64 + w * 16) * 32]);
                async_load16(Bg + (size_t)(i * 64 + w * 16) * K + (k0 + 32), &Bs[cur ^ 1][(i * 64 + w * 16) * 32]);
            }
        }
        bf16x8 af[4], bfr[4];
#pragma unroll
        for (int m = 0; m < 4; ++m)
            af[m] = *(const bf16x8*)&As[cur][(wr * 64 + m * 16 + (lane & 15)) * 32 + (lane >> 4) * 8];
#pragma unroll
        for (int n = 0; n < 4; ++n)
            bfr[n] = *(const bf16x8*)&Bs[cur][(wc * 64 + n * 16 + (lane & 15)) * 32 + (lane >> 4) * 8];
#pragma unroll
        for (int m = 0; m < 4; ++m)
#pragma unroll
            for (int n = 0; n < 4; ++n)
                acc[m][n] = MFMA16(af[m], bfr[n], acc[m][n]);
        __syncthreads();   // drains next-tile vmcnt + orders buffer reuse
        cur ^= 1;
    }

    int trow = row0 + wr * 64 + ((lane >> 4) * 4);
    int tcol = col0 + wc * 64 + (lane & 15);
#pragma unroll
    for (int m = 0; m < 4; ++m)
#pragma unroll
        for (int n = 0; n < 4; ++n) {
            int cg = tcol + n * 16;
            float bi = bias[cg];
#pragma unroll
            for (int j = 0; j < 4; ++j) {
                int rg = trow + m * 16 + j;
                float val = acc[m][n][j] + bi;
                int b = rg >> 11, tt = rg & 2047;
                if (cg < 1024) {
                    int h = cg >> 6, d = cg & 63;
                    size_t base = (size_t)(b * 16 + h) * 131072;
                    size_t idx = base + (size_t)((((tt >> 5) * 4 + (d >> 4)) * 64 + ((d >> 3) & 1) * 32 + (tt & 31)) * 8 + (d & 7));
                    qo[idx] = (bf16)(val * SCALE_Q);
                } else if (cg < 2048) {
                    int c2 = cg - 1024;
                    int h = c2 >> 6, d = c2 & 63;
                    size_t base = (size_t)(b * 16 + h) * 131072;
                    size_t idx = base + (size_t)((((tt >> 5) * 4 + (d >> 4)) * 64 + ((d >> 3) & 1) * 32 + (tt & 31)) * 8 + (d & 7));
                    ko[idx] = (bf16)val;
                } else {
                    int c2 = cg - 2048;
                    int h = c2 >> 6, d = c2 & 63;
                    size_t base = (size_t)(b * 16 + h) * 131072;
                    size_t idx = base + (size_t)(((((tt >> 6) * 4 + ((tt >> 4) & 3)) * 2 + (d >> 5)) * 64 + ((tt >> 3) & 1) * 32 + (d & 31)) * 8 + (tt & 7));
                    vo[idx] = (bf16)val;
                }
            }
        }
}

// ---------------- flash attention (causal), LDS-shared K/V tiles (r7, unchanged) ----------------
__global__ __launch_bounds__(256, 2) void k_attn(
    const bf16* __restrict__ qp, const bf16* __restrict__ kp,
    const bf16* __restrict__ vp, bf16* __restrict__ y) {
    __shared__ __align__(16) bf16 Ks[2][4096];
    __shared__ __align__(16) bf16 Vs[2][4096];
    int bh = blockIdx.y;
    int b = bh >> 4;
    int lane = threadIdx.x & 63, w = threadIdx.x >> 6;
    int tl = lane & 31, hi = lane >> 5;
    int lane8 = lane * 8;
    const bf16* Qb = qp + (size_t)bh * 131072;
    const bf16* Kb = kp + (size_t)bh * 131072;
    const bf16* Vb = vp + (size_t)bh * 131072;

    for (int qpass = 0; qpass < 2; ++qpass) {
        int qt0 = (qpass ? 15 - (int)blockIdx.x : (int)blockIdx.x) * 128;
        int trow0 = qt0 + w * 32;
        int t_g = trow0 + tl;

        bf16x8 qf[4];
        int qs = (trow0 >> 5) * 4;
#pragma unroll
        for (int kc = 0; kc < 4; ++kc)
            qf[kc] = *(const bf16x8*)&Qb[(qs + kc) * 512 + lane8];

        f32x16 o[2] = {};
        float m = -1e30f, l = 0.f;
        int ntb = (qt0 >> 6) + 2;
        int cur = 0;

#pragma unroll
        for (int i = 0; i < 2; ++i) {
            int u = 2 * w + i;
            async_load16(Kb + (size_t)u * 512 + lane8, &Ks[0][u * 512]);
            async_load16(Vb + (size_t)u * 512 + lane8, &Vs[0][u * 512]);
        }
        __syncthreads();

        for (int ti = 0; ti < ntb; ++ti) {
            int s0 = ti * 64;
            if (ti + 1 < ntb) {
#pragma unroll
                for (int i = 0; i < 2; ++i) {
                    int u = 2 * w + i;
                    async_load16(Kb + (size_t)((ti + 1) * 8 + u) * 512 + lane8, &Ks[cur ^ 1][u * 512]);
                    async_load16(Vb + (size_t)((ti + 1) * 8 + u) * 512 + lane8, &Vs[cur ^ 1][u * 512]);
                }
            }
            if (s0 < trow0 + 32) {
                f32x16 accs[2] = {};
                __builtin_amdgcn_s_setprio(1);
#pragma unroll
                for (int st = 0; st < 2; ++st)
#pragma unroll
                    for (int kc = 0; kc < 4; ++kc) {
                        bf16x8 kf = *(const bf16x8*)&Ks[cur][(st * 4 + kc) * 512 + lane8];
                        accs[st] = MFMA32(kf, qf[kc], accs[st]);
                    }
                __builtin_amdgcn_s_setprio(0);

                if (s0 + 63 > trow0) {
#pragma unroll
                    for (int st = 0; st < 2; ++st)
#pragma unroll
                        for (int r = 0; r < 16; ++r) {
                            int s = s0 + st * 32 + (r & 3) + 8 * (r >> 2) + 4 * hi;
                            if (s > t_g) accs[st][r] = -1e30f;
                        }
                }
                float pmax = -1e30f;
#pragma unroll
                for (int st = 0; st < 2; ++st)
#pragma unroll
                    for (int r = 0; r < 16; ++r)
                        pmax = fmaxf(pmax, accs[st][r]);
                pmax = fmaxf(pmax, __shfl_xor(pmax, 32));
                if (!__all(pmax <= m + 8.0f)) {
                    float mn = fmaxf(m, pmax);
                    float corr = __builtin_amdgcn_exp2f(m - mn);
                    m = mn;
                    l *= corr;
#pragma unroll
                    for (int dt = 0; dt < 2; ++dt)
#pragma unroll
                        for (int r = 0; r < 16; ++r)
                            o[dt][r] *= corr;
                }
                float ls = 0.f;
#pragma unroll
                for (int st = 0; st < 2; ++st)
#pragma unroll
                    for (int r = 0; r < 16; ++r) {
                        float p = __builtin_amdgcn_exp2f(accs[st][r] - m);
                        accs[st][r] = p;
                        ls += p;
                    }
                ls += __shfl_xor(ls, 32);
                l += ls;

                unsigned int pk[16];
#pragma unroll
                for (int st = 0; st < 2; ++st)
#pragma unroll
                    for (int q = 0; q < 8; ++q)
                        pk[st * 8 + q] = pack2bf(accs[st][2 * q], accs[st][2 * q + 1]);
                unsigned int rv[8];
#pragma unroll
                for (int st = 0; st < 2; ++st)
#pragma unroll
                    for (int i = 0; i < 4; ++i) {
                        int base = st * 8 + (i < 2 ? i : i + 2);
                        unsigned int send = hi ? pk[base] : pk[base + 2];
                        rv[st * 4 + i] = __shfl_xor(send, 32);
                    }
                __builtin_amdgcn_s_setprio(1);
#pragma unroll
                for (int c = 0; c < 4; ++c) {
                    const int st = c >> 1, c2 = c & 1;
                    uint32x4 pw;
                    pw.x = hi ? rv[st * 4 + 2 * c2]     : pk[st * 8 + 4 * c2];
                    pw.y = hi ? rv[st * 4 + 2 * c2 + 1] : pk[st * 8 + 4 * c2 + 1];
                    pw.z = hi ? pk[st * 8 + 4 * c2 + 2] : rv[st * 4 + 2 * c2];
                    pw.w = hi ? pk[st * 8 + 4 * c2 + 3] : rv[st * 4 + 2 * c2 + 1];
                    bf16x8 pf = __builtin_bit_cast(bf16x8, pw);
#pragma unroll
                    for (int dt = 0; dt < 2; ++dt) {
                        bf16x8 vf = *(const bf16x8*)&Vs[cur][(c * 2 + dt) * 512 + lane8];
                        o[dt] = MFMA32(vf, pf, o[dt]);
                    }
                }
                __builtin_amdgcn_s_setprio(0);
            }
            __syncthreads();
            cur ^= 1;
        }

        int hcol = (bh & 15) * 64;
        float inv = 1.0f / l;
        bf16* yr = y + (size_t)(b * 2048 + t_g) * 1024 + hcol;
#pragma unroll
        for (int dt = 0; dt < 2; ++dt)
#pragma unroll
            for (int rq = 0; rq < 4; ++rq) {
                bf16x4v ov;
#pragma unroll
                for (int ri = 0; ri < 4; ++ri)
                    ov[ri] = (bf16)(o[dt][rq * 4 + ri] * inv);
                *(bf16x4v*)&yr[dt * 32 + rq * 8 + hi * 4] = ov;
            }
    }
}

// ---------------- proj GEMM: prefetch-pipelined 2-phase, f32 epilogue ----------------
__global__ __launch_bounds__(256, 4) void k_gemm_proj(
    const bf16* __restrict__ A, const bf16* __restrict__ BT,
    const float* __restrict__ bias, float* __restrict__ out) {
    __shared__ bf16 As[2][128 * 32];
    __shared__ bf16 Bs[2][128 * 32];
    const int K = 1024;
    // XCD-chunked swizzle (bijective: 512 = 8 * 64)
    int orig = blockIdx.y * 8 + blockIdx.x;
    int wg = (orig & 7) * 64 + (orig >> 3);
    int row0 = (wg >> 3) * 128;
    int col0 = (wg & 7) * 128;
    int lane = threadIdx.x & 63, w = threadIdx.x >> 6;
    int wr = w >> 1, wc = w & 1;
    f32x4 acc[4][4] = {};
    const bf16* Ag = A + (size_t)(row0 + (lane >> 2)) * K + (lane & 3) * 8;
    const bf16* Bg = BT + (size_t)(col0 + (lane >> 2)) * K + (lane & 3) * 8;

#pragma unroll
    for (int i = 0; i < 2; ++i) {
        async_load16(Ag + (size_t)(i * 64 + w * 16) * K, &As[0][(i * 64 + w * 16) * 32]);
        async_load16(Bg + (size_t)(i * 64 + w * 16) * K, &Bs[0][(i * 64 + w * 16) * 32]);
    }
    __syncthreads();
    int cur = 0;

    for (int k0 = 0; k0 < K; k0 += 32) {
        if (k0 + 32 < K) {
#pragma unroll
            for (int i = 0; i < 2; ++i) {
                async_load16(Ag + (size_t)(i * 64 + w * 16) * K + (k0 + 32), &As[cur ^ 1][(i * 64 + w * 16) * 32]);
                async_load16(Bg + (size_t)(i * 64 + w * 16) * K + (k0 + 32), &Bs[cur ^ 1][(i * 64 + w * 16) * 32]);
            }
        }
        bf16x8 af[4], bfr[4];
#pragma unroll
        for (int m = 0; m < 4; ++m)
            af[m] = *(const bf16x8*)&As[cur][(wr * 64 + m * 16 + (lane & 15)) * 32 + (lane >> 4) * 8];
#pragma unroll
        for (int n = 0; n < 4; ++n)
            bfr[n] = *(const bf16x8*)&Bs[cur][(wc * 64 + n * 16 + (lane & 15)) * 32 + (lane >> 4) * 8];
#pragma unroll
        for (int m = 0; m < 4; ++m)
#pragma unroll
            for (int n = 0; n < 4; ++n)
                acc[m][n] = MFMA16(af[m], bfr[n], acc[m][n]);
        __syncthreads();
        cur ^= 1;
    }

    int trow = row0 + wr * 64 + ((lane >> 4) * 4);
    int tcol = col0 + wc * 64 + (lane & 15);
#pragma unroll
    for (int m = 0; m < 4; ++m)
#pragma unroll
        for (int n = 0; n < 4; ++n) {
            int cg = tcol + n * 16;
            float bi = bias[cg];
#pragma unroll
            for (int j = 0; j < 4; ++j) {
                int rg = trow + m * 16 + j;
                out[(size_t)rg * 1024 + cg] = acc[m][n][j] + bi;
            }
        }
}

extern "C" void kernel_launch(void* const* d_in, const int* in_sizes, int n_in,
                              void* d_out, int out_size, void* d_ws, size_t ws_size,
                              hipStream_t stream) {
    const float* x = (const float*)d_in[0];
    const float* W_attn = (const float*)d_in[1];
    const float* b_attn = (const float*)d_in[2];
    const float* W_proj = (const float*)d_in[3];
    const float* b_proj = (const float*)d_in[4];
    float* out = (float*)d_out;
    float* out_mem = out + (size_t)8388608;

    char* ws = (char*)d_ws;
    bf16* xb  = (bf16*)(ws);                         // 16MB  [8192][1024]
    bf16* WaT = (bf16*)(ws + ((size_t)16 << 20));    // 6MB   [3072][1024]
    bf16* WpT = (bf16*)(ws + ((size_t)22 << 20));    // 2MB   [1024][1024]
    bf16* q   = (bf16*)(ws + ((size_t)24 << 20));    // 16MB  packed frags
    bf16* k   = (bf16*)(ws + ((size_t)40 << 20));    // 16MB  packed frags
    bf16* vT  = (bf16*)(ws + ((size_t)56 << 20));    // 16MB  packed frags
    bf16* y   = (bf16*)(ws + ((size_t)72 << 20));    // 16MB  [8192][1024]

    k_cast_x<<<8192, 256, 0, stream>>>(x, xb, out_mem);
    k_trans_cast<<<dim3(96, 32), 256, 0, stream>>>(W_attn, WaT, 1024, 3072);
    k_trans_cast<<<dim3(32, 32), 256, 0, stream>>>(W_proj, WpT, 1024, 1024);
    k_gemm_qkv<<<dim3(24, 64), 256, 0, stream>>>(xb, WaT, b_attn, q, k, vT);
    k_attn<<<dim3(8, 64), 256, 0, stream>>>(q, k, vT, y);
    k_gemm_proj<<<dim3(8, 64), 256, 0, stream>>>(y, WpT, b_proj, out);
}

// Round 9
// 188.362 us; speedup vs baseline: 1.9581x; 1.0356x over previous
//
#include <hip/hip_runtime.h>
#include <hip/hip_bf16.h>

typedef __bf16 bf16;
typedef __bf16 bf16x8 __attribute__((ext_vector_type(8)));
typedef __bf16 bf16x4v __attribute__((ext_vector_type(4)));
typedef float f32x4 __attribute__((ext_vector_type(4)));
typedef float f32x16 __attribute__((ext_vector_type(16)));
typedef float float4v __attribute__((ext_vector_type(4)));
typedef unsigned int uint32x4 __attribute__((ext_vector_type(4)));

#define MFMA16(a, b, c) __builtin_amdgcn_mfma_f32_16x16x32_bf16(a, b, c, 0, 0, 0)
#define MFMA32(a, b, c) __builtin_amdgcn_mfma_f32_32x32x16_bf16(a, b, c, 0, 0, 0)

// q pre-scale: 1/sqrt(64) * log2(e)  (softmax runs in exp2 domain)
#define SCALE_Q 0.1803368801111f

__device__ __forceinline__ void async_load16(const bf16* g, bf16* l) {
    __builtin_amdgcn_global_load_lds(
        (const __attribute__((address_space(1))) void*)g,
        (__attribute__((address_space(3))) void*)l,
        16, 0, 0);
}

__device__ __forceinline__ unsigned int pack2bf(float a, float b) {
    bf16 x = (bf16)a, y = (bf16)b;
    unsigned short ux = __builtin_bit_cast(unsigned short, x);
    unsigned short uy = __builtin_bit_cast(unsigned short, y);
    return (unsigned int)ux | ((unsigned int)uy << 16);
}

// ---------------- fused preprocessing: cast x (+ new_memory copy) + W transposes ----------------
__global__ void k_pre(const float* __restrict__ x, const float* __restrict__ W_attn,
                      const float* __restrict__ W_proj,
                      bf16* __restrict__ xb, float* __restrict__ out_mem,
                      bf16* __restrict__ WaT, bf16* __restrict__ WpT) {
    __shared__ float tile[32][33];
    int bid = blockIdx.x;
    if (bid < 8192) {
        int i = bid * 256 + threadIdx.x;     // float4 index, 2097152 total
        float4v v = ((const float4v*)x)[i];
        bf16x4v o;
        o.x = (bf16)v.x; o.y = (bf16)v.y; o.z = (bf16)v.z; o.w = (bf16)v.w;
        ((bf16x4v*)xb)[i] = o;
        int rem = i & 524287;
        if (rem >= 393216) {
            int b = i >> 19;
            ((float4v*)out_mem)[(size_t)b * 131072 + (rem - 393216)] = v;
        }
        return;
    }
    const float* W;  bf16* WT;  int R, Cc, bx, by;
    if (bid < 8192 + 3072) {
        int idx = bid - 8192;
        W = W_attn; WT = WaT; R = 1024; Cc = 3072; bx = idx % 96; by = idx / 96;
    } else {
        int idx = bid - 11264;
        W = W_proj; WT = WpT; R = 1024; Cc = 1024; bx = idx & 31; by = idx >> 5;
    }
    int r0 = by * 32, c0 = bx * 32;
    int tx = threadIdx.x & 31, ty = threadIdx.x >> 5;
#pragma unroll
    for (int i = 0; i < 32; i += 8)
        tile[ty + i][tx] = W[(size_t)(r0 + ty + i) * Cc + c0 + tx];
    __syncthreads();
#pragma unroll
    for (int i = 0; i < 32; i += 8)
        WT[(size_t)(c0 + ty + i) * R + r0 + tx] = (bf16)tile[tx][ty + i];
}

// ---------------- QKV GEMM: counted-vmcnt pipeline + swizzled fragment reads ----------------
__global__ __launch_bounds__(256, 4) void k_gemm_qkv(
    const bf16* __restrict__ A, const bf16* __restrict__ BT,
    const float* __restrict__ bias,
    bf16* __restrict__ qo, bf16* __restrict__ ko, bf16* __restrict__ vo) {
    __shared__ bf16 As[2][4096];
    __shared__ bf16 Bs[2][4096];
    const int K = 1024;
    // XCD-chunked swizzle (bijective: 1536 = 8 * 192)
    int orig = blockIdx.y * 24 + blockIdx.x;
    int wg = (orig & 7) * 192 + (orig >> 3);
    int row0 = (wg / 24) * 128;
    int col0 = (wg % 24) * 128;
    int lane = threadIdx.x & 63, w = threadIdx.x >> 6;
    int wr = w >> 1, wc = w & 1;
    f32x4 acc[4][4] = {};
    // staging source: row = base + (lane>>2); 16B slot XOR-swizzled so swizzled
    // reads see linear data (involution both sides; LDS dest stays linear)
    int sslot = (lane & 3) ^ ((lane >> 3) & 3);
    const bf16* Ag = A + (size_t)(row0 + (lane >> 2)) * K + sslot * 8;
    const bf16* Bg = BT + (size_t)(col0 + (lane >> 2)) * K + sslot * 8;
    // fragment-read slot (per-lane constant): quarter ^ row-derived key
    int rslot = (lane >> 4) ^ ((lane >> 1) & 3);

#define STAGE_QKV(buf, k0)                                                            \
    {                                                                                 \
        async_load16(Ag + (size_t)(w * 16) * K + (k0), &As[buf][(w * 16) * 32]);      \
        async_load16(Ag + (size_t)(64 + w * 16) * K + (k0), &As[buf][(64 + w * 16) * 32]); \
        async_load16(Bg + (size_t)(w * 16) * K + (k0), &Bs[buf][(w * 16) * 32]);      \
        async_load16(Bg + (size_t)(64 + w * 16) * K + (k0), &Bs[buf][(64 + w * 16) * 32]); \
    }

    STAGE_QKV(0, 0)
    STAGE_QKV(1, 32)
    asm volatile("s_waitcnt vmcnt(4)" ::: "memory");   // tile 0 landed; tile 1 in flight
    __builtin_amdgcn_sched_barrier(0);
    __builtin_amdgcn_s_barrier();
    __builtin_amdgcn_sched_barrier(0);

    int cur = 0;
    for (int t = 0; t < 32; ++t) {
        bf16x8 af[4], bfr[4];
#pragma unroll
        for (int m = 0; m < 4; ++m)
            af[m] = *(const bf16x8*)&As[cur][(wr * 64 + m * 16 + (lane & 15)) * 32 + rslot * 8];
#pragma unroll
        for (int n = 0; n < 4; ++n)
            bfr[n] = *(const bf16x8*)&Bs[cur][(wc * 64 + n * 16 + (lane & 15)) * 32 + rslot * 8];
        __builtin_amdgcn_s_setprio(1);
#pragma unroll
        for (int m = 0; m < 4; ++m)
#pragma unroll
            for (int n = 0; n < 4; ++n)
                acc[m][n] = MFMA16(af[m], bfr[n], acc[m][n]);
        __builtin_amdgcn_s_setprio(0);
        asm volatile("s_waitcnt lgkmcnt(0)" ::: "memory");
        __builtin_amdgcn_sched_barrier(0);
        __builtin_amdgcn_s_barrier();          // B2: all waves done reading buf[cur]
        __builtin_amdgcn_sched_barrier(0);
        if (t + 2 < 32) {
            STAGE_QKV(cur, (t + 2) * 32)       // overwrite buf[cur] with tile t+2
            asm volatile("s_waitcnt vmcnt(4)" ::: "memory");   // tile t+1 landed
        } else {
            asm volatile("s_waitcnt vmcnt(0)" ::: "memory");
        }
        __builtin_amdgcn_sched_barrier(0);
        __builtin_amdgcn_s_barrier();          // B1: buf[cur^1] ready for all
        __builtin_amdgcn_sched_barrier(0);
        cur ^= 1;
    }

    int trow = row0 + wr * 64 + ((lane >> 4) * 4);
    int tcol = col0 + wc * 64 + (lane & 15);
#pragma unroll
    for (int m = 0; m < 4; ++m)
#pragma unroll
        for (int n = 0; n < 4; ++n) {
            int cg = tcol + n * 16;
            float bi = bias[cg];
#pragma unroll
            for (int j = 0; j < 4; ++j) {
                int rg = trow + m * 16 + j;
                float val = acc[m][n][j] + bi;
                int b = rg >> 11, tt = rg & 2047;
                if (cg < 1024) {
                    int h = cg >> 6, d = cg & 63;
                    size_t base = (size_t)(b * 16 + h) * 131072;
                    size_t idx = base + (size_t)((((tt >> 5) * 4 + (d >> 4)) * 64 + ((d >> 3) & 1) * 32 + (tt & 31)) * 8 + (d & 7));
                    qo[idx] = (bf16)(val * SCALE_Q);
                } else if (cg < 2048) {
                    int c2 = cg - 1024;
                    int h = c2 >> 6, d = c2 & 63;
                    size_t base = (size_t)(b * 16 + h) * 131072;
                    size_t idx = base + (size_t)((((tt >> 5) * 4 + (d >> 4)) * 64 + ((d >> 3) & 1) * 32 + (tt & 31)) * 8 + (d & 7));
                    ko[idx] = (bf16)val;
                } else {
                    int c2 = cg - 2048;
                    int h = c2 >> 6, d = c2 & 63;
                    size_t base = (size_t)(b * 16 + h) * 131072;
                    size_t idx = base + (size_t)(((((tt >> 6) * 4 + ((tt >> 4) & 3)) * 2 + (d >> 5)) * 64 + ((tt >> 3) & 1) * 32 + (d & 31)) * 8 + (tt & 7));
                    vo[idx] = (bf16)val;
                }
            }
        }
}

// ---------------- flash attention (causal), LDS-shared K/V tiles (r7, unchanged) ----------------
__global__ __launch_bounds__(256, 2) void k_attn(
    const bf16* __restrict__ qp, const bf16* __restrict__ kp,
    const bf16* __restrict__ vp, bf16* __restrict__ y) {
    __shared__ __align__(16) bf16 Ks[2][4096];
    __shared__ __align__(16) bf16 Vs[2][4096];
    int bh = blockIdx.y;
    int b = bh >> 4;
    int lane = threadIdx.x & 63, w = threadIdx.x >> 6;
    int tl = lane & 31, hi = lane >> 5;
    int lane8 = lane * 8;
    const bf16* Qb = qp + (size_t)bh * 131072;
    const bf16* Kb = kp + (size_t)bh * 131072;
    const bf16* Vb = vp + (size_t)bh * 131072;

    for (int qpass = 0; qpass < 2; ++qpass) {
        int qt0 = (qpass ? 15 - (int)blockIdx.x : (int)blockIdx.x) * 128;
        int trow0 = qt0 + w * 32;
        int t_g = trow0 + tl;

        bf16x8 qf[4];
        int qs = (trow0 >> 5) * 4;
#pragma unroll
        for (int kc = 0; kc < 4; ++kc)
            qf[kc] = *(const bf16x8*)&Qb[(qs + kc) * 512 + lane8];

        f32x16 o[2] = {};
        float m = -1e30f, l = 0.f;
        int ntb = (qt0 >> 6) + 2;
        int cur = 0;

#pragma unroll
        for (int i = 0; i < 2; ++i) {
            int u = 2 * w + i;
            async_load16(Kb + (size_t)u * 512 + lane8, &Ks[0][u * 512]);
            async_load16(Vb + (size_t)u * 512 + lane8, &Vs[0][u * 512]);
        }
        __syncthreads();

        for (int ti = 0; ti < ntb; ++ti) {
            int s0 = ti * 64;
            if (ti + 1 < ntb) {
#pragma unroll
                for (int i = 0; i < 2; ++i) {
                    int u = 2 * w + i;
                    async_load16(Kb + (size_t)((ti + 1) * 8 + u) * 512 + lane8, &Ks[cur ^ 1][u * 512]);
                    async_load16(Vb + (size_t)((ti + 1) * 8 + u) * 512 + lane8, &Vs[cur ^ 1][u * 512]);
                }
            }
            if (s0 < trow0 + 32) {
                f32x16 accs[2] = {};
                __builtin_amdgcn_s_setprio(1);
#pragma unroll
                for (int st = 0; st < 2; ++st)
#pragma unroll
                    for (int kc = 0; kc < 4; ++kc) {
                        bf16x8 kf = *(const bf16x8*)&Ks[cur][(st * 4 + kc) * 512 + lane8];
                        accs[st] = MFMA32(kf, qf[kc], accs[st]);
                    }
                __builtin_amdgcn_s_setprio(0);

                if (s0 + 63 > trow0) {
#pragma unroll
                    for (int st = 0; st < 2; ++st)
#pragma unroll
                        for (int r = 0; r < 16; ++r) {
                            int s = s0 + st * 32 + (r & 3) + 8 * (r >> 2) + 4 * hi;
                            if (s > t_g) accs[st][r] = -1e30f;
                        }
                }
                float pmax = -1e30f;
#pragma unroll
                for (int st = 0; st < 2; ++st)
#pragma unroll
                    for (int r = 0; r < 16; ++r)
                        pmax = fmaxf(pmax, accs[st][r]);
                pmax = fmaxf(pmax, __shfl_xor(pmax, 32));
                if (!__all(pmax <= m + 8.0f)) {
                    float mn = fmaxf(m, pmax);
                    float corr = __builtin_amdgcn_exp2f(m - mn);
                    m = mn;
                    l *= corr;
#pragma unroll
                    for (int dt = 0; dt < 2; ++dt)
#pragma unroll
                        for (int r = 0; r < 16; ++r)
                            o[dt][r] *= corr;
                }
                float ls = 0.f;
#pragma unroll
                for (int st = 0; st < 2; ++st)
#pragma unroll
                    for (int r = 0; r < 16; ++r) {
                        float p = __builtin_amdgcn_exp2f(accs[st][r] - m);
                        accs[st][r] = p;
                        ls += p;
                    }
                ls += __shfl_xor(ls, 32);
                l += ls;

                unsigned int pk[16];
#pragma unroll
                for (int st = 0; st < 2; ++st)
#pragma unroll
                    for (int q = 0; q < 8; ++q)
                        pk[st * 8 + q] = pack2bf(accs[st][2 * q], accs[st][2 * q + 1]);
                unsigned int rv[8];
#pragma unroll
                for (int st = 0; st < 2; ++st)
#pragma unroll
                    for (int i = 0; i < 4; ++i) {
                        int base = st * 8 + (i < 2 ? i : i + 2);
                        unsigned int send = hi ? pk[base] : pk[base + 2];
                        rv[st * 4 + i] = __shfl_xor(send, 32);
                    }
                __builtin_amdgcn_s_setprio(1);
#pragma unroll
                for (int c = 0; c < 4; ++c) {
                    const int st = c >> 1, c2 = c & 1;
                    uint32x4 pw;
                    pw.x = hi ? rv[st * 4 + 2 * c2]     : pk[st * 8 + 4 * c2];
                    pw.y = hi ? rv[st * 4 + 2 * c2 + 1] : pk[st * 8 + 4 * c2 + 1];
                    pw.z = hi ? pk[st * 8 + 4 * c2 + 2] : rv[st * 4 + 2 * c2];
                    pw.w = hi ? pk[st * 8 + 4 * c2 + 3] : rv[st * 4 + 2 * c2 + 1];
                    bf16x8 pf = __builtin_bit_cast(bf16x8, pw);
#pragma unroll
                    for (int dt = 0; dt < 2; ++dt) {
                        bf16x8 vf = *(const bf16x8*)&Vs[cur][(c * 2 + dt) * 512 + lane8];
                        o[dt] = MFMA32(vf, pf, o[dt]);
                    }
                }
                __builtin_amdgcn_s_setprio(0);
            }
            __syncthreads();
            cur ^= 1;
        }

        int hcol = (bh & 15) * 64;
        float inv = 1.0f / l;
        bf16* yr = y + (size_t)(b * 2048 + t_g) * 1024 + hcol;
#pragma unroll
        for (int dt = 0; dt < 2; ++dt)
#pragma unroll
            for (int rq = 0; rq < 4; ++rq) {
                bf16x4v ov;
#pragma unroll
                for (int ri = 0; ri < 4; ++ri)
                    ov[ri] = (bf16)(o[dt][rq * 4 + ri] * inv);
                *(bf16x4v*)&yr[dt * 32 + rq * 8 + hi * 4] = ov;
            }
    }
}

// ---------------- proj GEMM: counted-vmcnt pipeline + swizzled fragment reads ----------------
__global__ __launch_bounds__(256, 4) void k_gemm_proj(
    const bf16* __restrict__ A, const bf16* __restrict__ BT,
    const float* __restrict__ bias, float* __restrict__ out) {
    __shared__ bf16 As[2][4096];
    __shared__ bf16 Bs[2][4096];
    const int K = 1024;
    // XCD-chunked swizzle (bijective: 512 = 8 * 64)
    int orig = blockIdx.y * 8 + blockIdx.x;
    int wg = (orig & 7) * 64 + (orig >> 3);
    int row0 = (wg >> 3) * 128;
    int col0 = (wg & 7) * 128;
    int lane = threadIdx.x & 63, w = threadIdx.x >> 6;
    int wr = w >> 1, wc = w & 1;
    f32x4 acc[4][4] = {};
    int sslot = (lane & 3) ^ ((lane >> 3) & 3);
    const bf16* Ag = A + (size_t)(row0 + (lane >> 2)) * K + sslot * 8;
    const bf16* Bg = BT + (size_t)(col0 + (lane >> 2)) * K + sslot * 8;
    int rslot = (lane >> 4) ^ ((lane >> 1) & 3);

    STAGE_QKV(0, 0)
    STAGE_QKV(1, 32)
    asm volatile("s_waitcnt vmcnt(4)" ::: "memory");
    __builtin_amdgcn_sched_barrier(0);
    __builtin_amdgcn_s_barrier();
    __builtin_amdgcn_sched_barrier(0);

    int cur = 0;
    for (int t = 0; t < 32; ++t) {
        bf16x8 af[4], bfr[4];
#pragma unroll
        for (int m = 0; m < 4; ++m)
            af[m] = *(const bf16x8*)&As[cur][(wr * 64 + m * 16 + (lane & 15)) * 32 + rslot * 8];
#pragma unroll
        for (int n = 0; n < 4; ++n)
            bfr[n] = *(const bf16x8*)&Bs[cur][(wc * 64 + n * 16 + (lane & 15)) * 32 + rslot * 8];
        __builtin_amdgcn_s_setprio(1);
#pragma unroll
        for (int m = 0; m < 4; ++m)
#pragma unroll
            for (int n = 0; n < 4; ++n)
                acc[m][n] = MFMA16(af[m], bfr[n], acc[m][n]);
        __builtin_amdgcn_s_setprio(0);
        asm volatile("s_waitcnt lgkmcnt(0)" ::: "memory");
        __builtin_amdgcn_sched_barrier(0);
        __builtin_amdgcn_s_barrier();
        __builtin_amdgcn_sched_barrier(0);
        if (t + 2 < 32) {
            STAGE_QKV(cur, (t + 2) * 32)
            asm volatile("s_waitcnt vmcnt(4)" ::: "memory");
        } else {
            asm volatile("s_waitcnt vmcnt(0)" ::: "memory");
        }
        __builtin_amdgcn_sched_barrier(0);
        __builtin_amdgcn_s_barrier();
        __builtin_amdgcn_sched_barrier(0);
        cur ^= 1;
    }

    int trow = row0 + wr * 64 + ((lane >> 4) * 4);
    int tcol = col0 + wc * 64 + (lane & 15);
#pragma unroll
    for (int m = 0; m < 4; ++m)
#pragma unroll
        for (int n = 0; n < 4; ++n) {
            int cg = tcol + n * 16;
            float bi = bias[cg];
#pragma unroll
            for (int j = 0; j < 4; ++j) {
                int rg = trow + m * 16 + j;
                out[(size_t)rg * 1024 + cg] = acc[m][n][j] + bi;
            }
        }
}

extern "C" void kernel_launch(void* const* d_in, const int* in_sizes, int n_in,
                              void* d_out, int out_size, void* d_ws, size_t ws_size,
                              hipStream_t stream) {
    const float* x = (const float*)d_in[0];
    const float* W_attn = (const float*)d_in[1];
    const float* b_attn = (const float*)d_in[2];
    const float* W_proj = (const float*)d_in[3];
    const float* b_proj = (const float*)d_in[4];
    float* out = (float*)d_out;
    float* out_mem = out + (size_t)8388608;

    char* ws = (char*)d_ws;
    bf16* xb  = (bf16*)(ws);                         // 16MB  [8192][1024]
    bf16* WaT = (bf16*)(ws + ((size_t)16 << 20));    // 6MB   [3072][1024]
    bf16* WpT = (bf16*)(ws + ((size_t)22 << 20));    // 2MB   [1024][1024]
    bf16* q   = (bf16*)(ws + ((size_t)24 << 20));    // 16MB  packed frags
    bf16* k   = (bf16*)(ws + ((size_t)40 << 20));    // 16MB  packed frags
    bf16* vT  = (bf16*)(ws + ((size_t)56 << 20));    // 16MB  packed frags
    bf16* y   = (bf16*)(ws + ((size_t)72 << 20));    // 16MB  [8192][1024]

    k_pre<<<12288, 256, 0, stream>>>(x, W_attn, W_proj, xb, out_mem, WaT, WpT);
    k_gemm_qkv<<<dim3(24, 64), 256, 0, stream>>>(xb, WaT, b_attn, q, k, vT);
    k_attn<<<dim3(8, 64), 256, 0, stream>>>(q, k, vT, y);
    k_gemm_proj<<<dim3(8, 64), 256, 0, stream>>>(y, WpT, b_proj, out);
}